// Round 3
// baseline (3356.039 us; speedup 1.0000x reference)
//
#include <hip/hip_runtime.h>
#include <hip/hip_bf16.h>

using bf16 = __hip_bfloat16;
typedef short v8s __attribute__((ext_vector_type(8)));   // 8 bf16 = 4 VGPRs
typedef float v4f __attribute__((ext_vector_type(4)));   // MFMA C/D frag

__device__ __forceinline__ float sigmoidf_(float x) {
    return 1.0f / (1.0f + __expf(-x));
}
__device__ __forceinline__ float tanhf_(float x) {
    return 1.0f - 2.0f / (__expf(2.0f * x) + 1.0f);
}
__device__ __forceinline__ unsigned short bfbits(float f) {
    bf16 h = __float2bfloat16(f);
    return *reinterpret_cast<unsigned short*>(&h);
}
__device__ __forceinline__ float bf2f(unsigned short u) {
    bf16 h = *reinterpret_cast<bf16*>(&u);
    return __bfloat162float(h);
}
// sentinel: packed bf16 pair 0xFFFF,0xFFFF (-NaN). h = sigmoid*tanh is always
// finite in (-1,1); initial states are finite normals. A real packed h u32 can
// never equal 0xFFFFFFFF.
__device__ __forceinline__ bool hasSent(unsigned long long v) {
    return ((unsigned)v == 0xFFFFFFFFu) || ((unsigned)(v >> 32) == 0xFFFFFFFFu);
}

// ---------------- fp32 -> bf16 converter ----------------
__global__ void f2b_kernel(const float* __restrict__ s, bf16* __restrict__ d, int n) {
    int idx = blockIdx.x * blockDim.x + threadIdx.x;
    int stride = gridDim.x * blockDim.x;
    for (int i = idx * 4; i < n; i += stride * 4) {
        float4 v = *reinterpret_cast<const float4*>(s + i);
        ushort4 u;
        u.x = bfbits(v.x); u.y = bfbits(v.y); u.z = bfbits(v.z); u.w = bfbits(v.w);
        *reinterpret_cast<ushort4*>(d + i) = u;
    }
}

// ---------------- sentinel fill for write-once h histories ----------------
__global__ void fill_sentinel(uint4* __restrict__ p, int n16) {
    int i = blockIdx.x * blockDim.x + threadIdx.x;
    int stride = gridDim.x * blockDim.x;
    uint4 v; v.x = v.y = v.z = v.w = 0xFFFFFFFFu;
    for (; i < n16; i += stride) p[i] = v;
}

// ---------------- init states (slot 0) + flag arrays ----------------
__global__ void init_state_kernel(const float* __restrict__ eh, const float* __restrict__ ec,
                                  float* __restrict__ hf, float* __restrict__ cf,
                                  bf16* __restrict__ h0h, bf16* __restrict__ h1h,
                                  unsigned* __restrict__ flags) {
    int idx = blockIdx.x * blockDim.x + threadIdx.x;
    if (idx < 128) flags[idx] = 0u;   // 2 phases x 64 WG flags
    if (idx >= 2 * 32 * 512) return;
    int l = idx >> 14;          // / 16384
    int rem = idx & 16383;
    hf[idx] = eh[idx];
    cf[idx] = ec[idx];
    bf16 hv = __float2bfloat16(eh[idx]);
    if (!l) h0h[rem] = hv;      // history slot 0 = initial state
    else    h1h[rem] = hv;
}

// ---------------- tail: final states -> d_out ----------------
__global__ void tail_kernel(const float* __restrict__ hf, const float* __restrict__ cf,
                            float* __restrict__ out) {
    int idx = blockIdx.x * blockDim.x + threadIdx.x;
    if (idx >= 2 * 32 * 512) return;
    out[1048576 + idx] = hf[idx];
    out[1048576 + 32768 + idx] = cf[idx];
}

// ---------------- bf16 MFMA GEMM: C[M,N] = A[M,K] @ W[N,K]^T (+bias) ----------------
__global__ __launch_bounds__(256) void gemm_bt(
    const bf16* __restrict__ A, const bf16* __restrict__ W,
    const float* __restrict__ bias,
    float* __restrict__ Cf, bf16* __restrict__ Cb,
    int M, int N, int K) {
    __shared__ __align__(16) bf16 As[64][72];
    __shared__ __align__(16) bf16 Bs[64][72];
    const int tid = threadIdx.x;
    const int wave = tid >> 6, lane = tid & 63;
    const int lr = lane & 15, lq = lane >> 4;
    const int m0 = blockIdx.y * 64, n0 = blockIdx.x * 64;

    v4f acc[4];
#pragma unroll
    for (int n = 0; n < 4; ++n) acc[n] = (v4f){0.f, 0.f, 0.f, 0.f};

    for (int k0 = 0; k0 < K; k0 += 64) {
        __syncthreads();
#pragma unroll
        for (int c = tid; c < 512; c += 256) {
            int row = c >> 3, c8 = (c & 7) * 8;
            *reinterpret_cast<v8s*>(&As[row][c8]) =
                *reinterpret_cast<const v8s*>(A + (size_t)(m0 + row) * K + k0 + c8);
            *reinterpret_cast<v8s*>(&Bs[row][c8]) =
                *reinterpret_cast<const v8s*>(W + (size_t)(n0 + row) * K + k0 + c8);
        }
        __syncthreads();
#pragma unroll
        for (int kk = 0; kk < 2; ++kk) {
            v8s a = *reinterpret_cast<const v8s*>(&As[wave * 16 + lr][kk * 32 + lq * 8]);
#pragma unroll
            for (int n = 0; n < 4; ++n) {
                v8s b = *reinterpret_cast<const v8s*>(&Bs[n * 16 + lr][kk * 32 + lq * 8]);
                acc[n] = __builtin_amdgcn_mfma_f32_16x16x32_bf16(a, b, acc[n], 0, 0, 0);
            }
        }
    }
#pragma unroll
    for (int n = 0; n < 4; ++n) {
        int col = n0 + n * 16 + lr;
        float bv = bias ? bias[col] : 0.0f;
#pragma unroll
        for (int r = 0; r < 4; ++r) {
            int row = m0 + wave * 16 + lq * 4 + r;
            float v = acc[n][r] + bv;
            if (Cf) Cf[(size_t)row * N + col] = v;
            if (Cb) Cb[(size_t)row * N + col] = __float2bfloat16(v);
        }
    }
}

// ---------------- persistent 2-layer pipelined LSTM stack ----------------
// 64 WGs x 256 thr, co-resident. WGs 0..31: layer 0 (WG j owns hidden cols
// [j*16,j*16+16), wave w = gate w). WGs 32..63: layer 1.
//
// Hybrid sync protocol:
//  - h goes to write-once history slots prefilled with sentinel 0xFFFFFFFF.
//  - Producer: h store (relaxed agent) -> compiler fence -> RAW s_barrier
//    (execution only, NO vmcnt drain) -> tid0 posts flag = t+1. The flag means
//    "stores issued", not "stores visible".
//  - Consumer: issues plain CACHED prefetch of the h tile, then wave0 polls
//    flags (fast single-word detection), then all threads validate their
//    prefetched words against the sentinel and atomically reload stragglers
//    (agent atomic loads read through stale L1/L2 — proven by flag polling
//    working in prior rounds). Common case: zero reload rounds, and 8 WGs/XCD
//    share one L2 fill.
//  - Layers are DECOUPLED: layer0 polls only flags[0..31] (never waits for
//    layer1); layer1 needs own peers >= t and layer0 >= t+1. Write-once slots
//    mean layer0 can run arbitrarily far ahead (no WAR).
__global__ __launch_bounds__(256, 1) void lstm2_persist(
    int T, int t0,
    bf16* __restrict__ h0hist, bf16* __restrict__ h1hist, // write-once histories
    float* __restrict__ hf, float* __restrict__ cf,    // [2][32*512] fp32 state
    const bf16* __restrict__ Whh0,                     // [2048][512]
    const bf16* __restrict__ Wih1, const bf16* __restrict__ Whh1,
    const float* __restrict__ xpf,                     // layer0 fp32 xp [(b*T+t)*2048]
    const bf16* __restrict__ xpb,                      // layer0 bf16 xp (alt)
    const float* __restrict__ bih0, const float* __restrict__ bhh0,
    const float* __restrict__ bih1, const float* __restrict__ bhh1,
    float* __restrict__ outf, long out_stride_b,       // layer1 fp32 h seq (or null)
    unsigned* __restrict__ flags)                      // 64 per-WG step counters
{
    __shared__ __align__(16) bf16 hs_h[32][520];      // own h(t-1); +8 pad
    __shared__ __align__(16) bf16 hs_x[32][520];      // layer1: h0(t)
    __shared__ float gs[4][32][16];
    __shared__ float bias_s[4][16];

    const int tid = threadIdx.x;
    const int layer = blockIdx.x >> 5;
    const int jj = blockIdx.x & 31;
    const int wave = tid >> 6, lane = tid & 63;
    const int lr = lane & 15, lq = lane >> 4;
    const int hc0 = jj * 16;

    const float* bih_l = layer ? bih1 : bih0;
    const float* bhh_l = layer ? bhh1 : bhh0;
    if (tid < 64) {
        int g = tid >> 4, col = tid & 15;
        bias_s[g][col] = bih_l[g * 512 + hc0 + col] + bhh_l[g * 512 + hc0 + col];
    }

    // pointwise ownership: batch pb, cols pc & pc+1 (c register-resident)
    const int pb = tid >> 3;
    const int pc = (tid & 7) * 2;
    const int pgc = hc0 + pc;

    float* hf_l = hf + (size_t)layer * 16384;
    float* cf_l = cf + (size_t)layer * 16384;
    float c0, c1;
    {
        size_t sidx = (size_t)pb * 512 + pgc;
        c0 = cf_l[sidx]; c1 = cf_l[sidx + 1];
    }

    // Whh slice pinned in registers (64 VGPRs / thread).
    v8s breg_hh[16];
    {
        const bf16* Whh_l = layer ? Whh1 : Whh0;
        const bf16* wrow = Whh_l + (size_t)(wave * 512 + hc0 + lr) * 512 + lq * 8;
#pragma unroll
        for (int kk = 0; kk < 16; ++kk)
            breg_hh[kk] = *reinterpret_cast<const v8s*>(wrow + kk * 32);
    }
    // Layer1: Wih slice also in registers (64 more VGPRs; fine at 1 WG/CU).
    v8s breg_ih[16];
    if (layer) {
        const bf16* wrow = Wih1 + (size_t)(wave * 512 + hc0 + lr) * 512 + lq * 8;
#pragma unroll
        for (int kk = 0; kk < 16; ++kk)
            breg_ih[kk] = *reinterpret_cast<const v8s*>(wrow + kk * 32);
    }
    __syncthreads();

    // staging geometry: thread tid covers v8s at element tid*8 + i*2048,
    // LDS row (tid>>6)+4i, col (tid*8)&511; as u64s: index tid*2 + i*512 (+1)
    const int st_row = tid >> 6;
    const int st_col = (tid * 8) & 511;

    auto load_xp = [&](int t, float* xv) {
        if (xpf) {
            const float* xp = xpf + ((size_t)pb * T + t) * 2048;
            float2 a = *reinterpret_cast<const float2*>(xp + pgc);
            float2 b = *reinterpret_cast<const float2*>(xp + 512 + pgc);
            float2 c = *reinterpret_cast<const float2*>(xp + 1024 + pgc);
            float2 d = *reinterpret_cast<const float2*>(xp + 1536 + pgc);
            xv[0] = a.x; xv[1] = a.y; xv[2] = b.x; xv[3] = b.y;
            xv[4] = c.x; xv[5] = c.y; xv[6] = d.x; xv[7] = d.y;
        } else {
            const bf16* xp = xpb + ((size_t)pb * T + t) * 2048;
            unsigned a = *reinterpret_cast<const unsigned*>(xp + pgc);
            unsigned b = *reinterpret_cast<const unsigned*>(xp + 512 + pgc);
            unsigned c = *reinterpret_cast<const unsigned*>(xp + 1024 + pgc);
            unsigned d = *reinterpret_cast<const unsigned*>(xp + 1536 + pgc);
            xv[0] = bf2f(a & 0xffff); xv[1] = bf2f(a >> 16);
            xv[2] = bf2f(b & 0xffff); xv[3] = bf2f(b >> 16);
            xv[4] = bf2f(c & 0xffff); xv[5] = bf2f(c >> 16);
            xv[6] = bf2f(d & 0xffff); xv[7] = bf2f(d >> 16);
        }
    };

    float xcur[8];
    if (!layer) load_xp(0, xcur);

    bf16* own_base = layer ? h1hist : h0hist;

    for (int t = 0; t < T; ++t) {
        const bf16* own_src = own_base + (size_t)(t0 + t) * 16384;       // h(t-1)
        bf16* own_dst       = own_base + (size_t)(t0 + t + 1) * 16384;   // h(t)

        // ---- cached prefetch of input tiles (issued BEFORE the flag poll,
        //      so the L2-miss->IC latency overlaps the poll window) ----
        const unsigned long long* srcH =
            reinterpret_cast<const unsigned long long*>(own_src);
        const unsigned long long* srcX = layer
            ? reinterpret_cast<const unsigned long long*>(
                  h0hist + (size_t)(t0 + t + 1) * 16384)                 // h0(t)
            : nullptr;
        unsigned long long rh[16], rx[16];
#pragma unroll
        for (int i = 0; i < 8; ++i) {
            rh[2 * i]     = srcH[tid * 2 + i * 512];
            rh[2 * i + 1] = srcH[tid * 2 + i * 512 + 1];
        }
        if (layer) {
#pragma unroll
            for (int i = 0; i < 8; ++i) {
                rx[2 * i]     = srcX[tid * 2 + i * 512];
                rx[2 * i + 1] = srcX[tid * 2 + i * 512 + 1];
            }
        }

        // ---- flag poll: wave0 only, single word per lane ----
        if (tid < 64) {
            for (;;) {
                unsigned v = __hip_atomic_load(&flags[layer ? tid : (tid & 31)],
                                 __ATOMIC_RELAXED, __HIP_MEMORY_SCOPE_AGENT);
                bool ok;
                if (layer)
                    ok = (tid < 32) ? (v >= (unsigned)(t + 1))   // layer0 >= t+1
                                    : (v >= (unsigned)t);        // own peers >= t
                else
                    ok = (v >= (unsigned)t);
                if (__all(ok)) break;
            }
        }
        __syncthreads();

        // ---- sentinel validation + atomic reload of stragglers ----
        for (;;) {
            bool again = false;
#pragma unroll
            for (int k = 0; k < 16; ++k) {
                if (hasSent(rh[k])) {
                    rh[k] = __hip_atomic_load(
                        srcH + tid * 2 + (k >> 1) * 512 + (k & 1),
                        __ATOMIC_RELAXED, __HIP_MEMORY_SCOPE_AGENT);
                    again = true;
                }
            }
            if (layer) {
#pragma unroll
                for (int k = 0; k < 16; ++k) {
                    if (hasSent(rx[k])) {
                        rx[k] = __hip_atomic_load(
                            srcX + tid * 2 + (k >> 1) * 512 + (k & 1),
                            __ATOMIC_RELAXED, __HIP_MEMORY_SCOPE_AGENT);
                        again = true;
                    }
                }
            }
            if (!again) break;
        }

        // ---- stage -> LDS ----
        if (layer) {
#pragma unroll
            for (int i = 0; i < 8; ++i) {
                union { unsigned long long u[2]; v8s v; } w;
                w.u[0] = rx[2 * i]; w.u[1] = rx[2 * i + 1];
                *reinterpret_cast<v8s*>(&hs_x[st_row + 4 * i][st_col]) = w.v;
            }
        }
#pragma unroll
        for (int i = 0; i < 8; ++i) {
            union { unsigned long long u[2]; v8s v; } w;
            w.u[0] = rh[2 * i]; w.u[1] = rh[2 * i + 1];
            *reinterpret_cast<v8s*>(&hs_h[st_row + 4 * i][st_col]) = w.v;
        }
        __syncthreads();

        // ---- gate GEMM from LDS; 4 independent MFMA chains for ILP ----
        v4f ax0 = (v4f){0.f, 0.f, 0.f, 0.f};
        v4f ax1 = (v4f){0.f, 0.f, 0.f, 0.f};
        v4f ah0 = (v4f){0.f, 0.f, 0.f, 0.f};
        v4f ah1 = (v4f){0.f, 0.f, 0.f, 0.f};
        if (layer) {
#pragma unroll
            for (int kk = 0; kk < 16; ++kk) {
                v8s a0x = *reinterpret_cast<const v8s*>(&hs_x[lr][lq * 8 + kk * 32]);
                v8s a1x = *reinterpret_cast<const v8s*>(&hs_x[16 + lr][lq * 8 + kk * 32]);
                ax0 = __builtin_amdgcn_mfma_f32_16x16x32_bf16(a0x, breg_ih[kk], ax0, 0, 0, 0);
                ax1 = __builtin_amdgcn_mfma_f32_16x16x32_bf16(a1x, breg_ih[kk], ax1, 0, 0, 0);
                v8s a0h = *reinterpret_cast<const v8s*>(&hs_h[lr][lq * 8 + kk * 32]);
                v8s a1h = *reinterpret_cast<const v8s*>(&hs_h[16 + lr][lq * 8 + kk * 32]);
                ah0 = __builtin_amdgcn_mfma_f32_16x16x32_bf16(a0h, breg_hh[kk], ah0, 0, 0, 0);
                ah1 = __builtin_amdgcn_mfma_f32_16x16x32_bf16(a1h, breg_hh[kk], ah1, 0, 0, 0);
            }
        } else {
#pragma unroll
            for (int kk = 0; kk < 16; kk += 2) {
                v8s a0e = *reinterpret_cast<const v8s*>(&hs_h[lr][lq * 8 + kk * 32]);
                v8s a1e = *reinterpret_cast<const v8s*>(&hs_h[16 + lr][lq * 8 + kk * 32]);
                ax0 = __builtin_amdgcn_mfma_f32_16x16x32_bf16(a0e, breg_hh[kk], ax0, 0, 0, 0);
                ax1 = __builtin_amdgcn_mfma_f32_16x16x32_bf16(a1e, breg_hh[kk], ax1, 0, 0, 0);
                v8s a0o = *reinterpret_cast<const v8s*>(&hs_h[lr][lq * 8 + (kk + 1) * 32]);
                v8s a1o = *reinterpret_cast<const v8s*>(&hs_h[16 + lr][lq * 8 + (kk + 1) * 32]);
                ah0 = __builtin_amdgcn_mfma_f32_16x16x32_bf16(a0o, breg_hh[kk + 1], ah0, 0, 0, 0);
                ah1 = __builtin_amdgcn_mfma_f32_16x16x32_bf16(a1o, breg_hh[kk + 1], ah1, 0, 0, 0);
            }
        }
        v4f acc0 = ax0 + ah0;
        v4f acc1 = ax1 + ah1;
#pragma unroll
        for (int r2 = 0; r2 < 4; ++r2) {
            gs[wave][lq * 4 + r2][lr]      = acc0[r2];
            gs[wave][16 + lq * 4 + r2][lr] = acc1[r2];
        }
        __syncthreads();

        // ---- pointwise: this thread's (pb, pc..pc+1) ----
        float xi0 = layer ? 0.f : xcur[0], xi1 = layer ? 0.f : xcur[1];
        float xf0 = layer ? 0.f : xcur[2], xf1 = layer ? 0.f : xcur[3];
        float xg0 = layer ? 0.f : xcur[4], xg1 = layer ? 0.f : xcur[5];
        float xo0 = layer ? 0.f : xcur[6], xo1 = layer ? 0.f : xcur[7];

        float gi0 = gs[0][pb][pc]     + xi0 + bias_s[0][pc];
        float gi1 = gs[0][pb][pc + 1] + xi1 + bias_s[0][pc + 1];
        float gf0 = gs[1][pb][pc]     + xf0 + bias_s[1][pc];
        float gf1 = gs[1][pb][pc + 1] + xf1 + bias_s[1][pc + 1];
        float gg0 = gs[2][pb][pc]     + xg0 + bias_s[2][pc];
        float gg1 = gs[2][pb][pc + 1] + xg1 + bias_s[2][pc + 1];
        float go0 = gs[3][pb][pc]     + xo0 + bias_s[3][pc];
        float go1 = gs[3][pb][pc + 1] + xo1 + bias_s[3][pc + 1];

        c0 = sigmoidf_(gf0) * c0 + sigmoidf_(gi0) * tanhf_(gg0);
        c1 = sigmoidf_(gf1) * c1 + sigmoidf_(gi1) * tanhf_(gg1);
        float h0v = sigmoidf_(go0) * tanhf_(c0);
        float h1v = sigmoidf_(go1) * tanhf_(c1);

        unsigned hp = (unsigned)bfbits(h0v) | ((unsigned)bfbits(h1v) << 16);
        __hip_atomic_store(reinterpret_cast<unsigned*>(own_dst + (size_t)pb * 512 + pgc),
                           hp, __ATOMIC_RELAXED, __HIP_MEMORY_SCOPE_AGENT);
        if (layer && outf) {
            float2 hv; hv.x = h0v; hv.y = h1v;
            *reinterpret_cast<float2*>(outf + (size_t)pb * out_stride_b + (size_t)t * 512 + pgc) = hv;
        }
        if (t == T - 1) {
            size_t sidx = (size_t)pb * 512 + pgc;
            hf_l[sidx] = h0v; hf_l[sidx + 1] = h1v;
            cf_l[sidx] = c0;  cf_l[sidx + 1] = c1;
        }

        // ---- early flag post: execution barrier only, NO vmcnt drain.
        // Compiler fence keeps the h store from moving below the barrier/flag;
        // in-flight reordering at the memory system is tolerated because
        // consumers sentinel-validate the data.
        asm volatile("" ::: "memory");
        __builtin_amdgcn_s_barrier();
        if (tid == 0)
            __hip_atomic_store(&flags[blockIdx.x], (unsigned)(t + 1),
                               __ATOMIC_RELAXED, __HIP_MEMORY_SCOPE_AGENT);
        // layer0: xp(t+1) prefetch; latency drains under next step's poll.
        if (!layer && t + 1 < T) load_xp(t + 1, xcur);
    }
}

// ---------------- host orchestration ----------------
extern "C" void kernel_launch(void* const* d_in, const int* in_sizes, int n_in,
                              void* d_out, int out_size, void* d_ws, size_t ws_size,
                              hipStream_t stream) {
    constexpr int B = 32, S = 512, F = 64, I = 512, H = 512, G = 2048;

    const float* x    = (const float*)d_in[0];
    const float* fut  = (const float*)d_in[1];
    const float* eh   = (const float*)d_in[2];
    const float* ec   = (const float*)d_in[3];
    const float* fc_w = (const float*)d_in[4];
    const float* fc_b = (const float*)d_in[5];
    const float* ewih = (const float*)d_in[6];
    const float* ewhh = (const float*)d_in[7];
    const float* ebih = (const float*)d_in[8];
    const float* ebhh = (const float*)d_in[9];
    const float* dwih = (const float*)d_in[10];
    const float* dwhh = (const float*)d_in[11];
    const float* dbih = (const float*)d_in[12];
    const float* dbhh = (const float*)d_in[13];
    float* out = (float*)d_out;

    char* ws = (char*)d_ws;
    size_t off = 0;
    auto alloc = [&](size_t bytes) -> char* {
        char* p = ws + off;
        off += (bytes + 255) & ~(size_t)255;
        return p;
    };

    bf16* x_bf    = (bf16*)alloc((size_t)B * S * I * 2);
    bf16* fut_bf  = (bf16*)alloc((size_t)B * F * I * 2);
    bf16* fcw_bf  = (bf16*)alloc((size_t)H * I * 2);
    bf16* ewih_bf = (bf16*)alloc((size_t)2 * G * H * 2);
    bf16* ewhh_bf = (bf16*)alloc((size_t)2 * G * H * 2);
    bf16* dwih_bf = (bf16*)alloc((size_t)2 * G * H * 2);
    bf16* dwhh_bf = (bf16*)alloc((size_t)2 * G * H * 2);
    bf16* xt_bf   = (bf16*)alloc((size_t)B * S * H * 2);
    float* hf     = (float*)alloc((size_t)2 * B * H * 4);
    float* cf     = (float*)alloc((size_t)2 * B * H * 4);
    unsigned* flags = (unsigned*)alloc(128 * sizeof(unsigned)); // 2 phases x 64

    // write-once h histories: (S+F+1) slots x [B*H] bf16 each (contiguous pair)
    size_t histb = (size_t)(S + F + 1) * B * H * 2;
    bf16* h0hist = (bf16*)alloc(histb);
    bf16* h1hist = (bf16*)alloc(histb);

    size_t xp32_bytes = (size_t)B * S * G * 4;
    bool xp32 = ws_size >= off + xp32_bytes + 4096;
    float* Xf = nullptr; bf16* Xb = nullptr;
    if (xp32) Xf = (float*)alloc(xp32_bytes);
    else      Xb = (bf16*)alloc((size_t)B * S * G * 2);

    auto cvt = [&](const float* s, bf16* d, int n) {
        int blocks = (n / 4 + 255) / 256;
        if (blocks > 4096) blocks = 4096;
        f2b_kernel<<<blocks, 256, 0, stream>>>(s, d, n);
    };
    cvt(x, x_bf, B * S * I);
    cvt(fut, fut_bf, B * F * I);
    cvt(fc_w, fcw_bf, H * I);
    cvt(ewih, ewih_bf, 2 * G * H);
    cvt(ewhh, ewhh_bf, 2 * G * H);
    cvt(dwih, dwih_bf, 2 * G * H);
    cvt(dwhh, dwhh_bf, 2 * G * H);

    // sentinel-fill both histories (contiguous), THEN write slot-0 states.
    fill_sentinel<<<2048, 256, 0, stream>>>(
        reinterpret_cast<uint4*>(h0hist), (int)(2 * histb / 16));
    init_state_kernel<<<128, 256, 0, stream>>>(eh, ec, hf, cf, h0hist, h1hist, flags);

    auto gemm = [&](const bf16* A, const bf16* W, const float* bias,
                    float* Cf_, bf16* Cb_, int M, int N, int K) {
        gemm_bt<<<dim3(N / 64, M / 64), 256, 0, stream>>>(A, W, bias, Cf_, Cb_, M, N, K);
    };

    // FC: xt = bf16(x @ fc_w^T + fc_b)
    gemm(x_bf, fcw_bf, fc_b, nullptr, xt_bf, B * S, H, I);

    // ---- Encoder: xp for layer 0 only, then decoupled 2-layer persist ----
    gemm(xt_bf, ewih_bf, nullptr, Xf, Xb, B * S, G, H);
    lstm2_persist<<<64, 256, 0, stream>>>(
        S, /*t0=*/0,
        h0hist, h1hist,
        hf, cf,
        ewhh_bf,                              // Whh0
        ewih_bf + (size_t)G * H,              // Wih1
        ewhh_bf + (size_t)G * H,              // Whh1
        Xf, Xb,
        ebih, ebhh, ebih + G, ebhh + G,
        nullptr, 0,
        flags + 0);

    // ---- Decoder: starts at slot S (= encoder's final h, already in place) ----
    gemm(fut_bf, dwih_bf, nullptr, Xf, Xb, B * F, G, H);
    lstm2_persist<<<64, 256, 0, stream>>>(
        F, /*t0=*/S,
        h0hist, h1hist,
        hf, cf,
        dwhh_bf,
        dwih_bf + (size_t)G * H,
        dwhh_bf + (size_t)G * H,
        Xf, Xb,
        dbih, dbhh, dbih + G, dbhh + G,
        out, (long)F * H,                     // dec_out [B,F,H] fp32
        flags + 64);

    // ---- Final decoder states ----
    tail_kernel<<<128, 256, 0, stream>>>(hf, cf, out);
}

// Round 4
// 2759.962 us; speedup vs baseline: 1.2160x; 1.2160x over previous
//
#include <hip/hip_runtime.h>
#include <hip/hip_bf16.h>

using bf16 = __hip_bfloat16;
typedef short v8s __attribute__((ext_vector_type(8)));   // 8 bf16 = 4 VGPRs
typedef float v4f __attribute__((ext_vector_type(4)));   // MFMA C/D frag

__device__ __forceinline__ float sigmoidf_(float x) {
    return 1.0f / (1.0f + __expf(-x));
}
__device__ __forceinline__ float tanhf_(float x) {
    return 1.0f - 2.0f / (__expf(2.0f * x) + 1.0f);
}
__device__ __forceinline__ unsigned short bfbits(float f) {
    bf16 h = __float2bfloat16(f);
    return *reinterpret_cast<unsigned short*>(&h);
}
__device__ __forceinline__ float bf2f(unsigned short u) {
    bf16 h = *reinterpret_cast<bf16*>(&u);
    return __bfloat162float(h);
}
// sentinel: packed bf16 pair 0xFFFF,0xFFFF (-NaN). h = sigmoid*tanh is always
// finite in (-1,1); initial states are finite normals. A real packed h u32 can
// never equal 0xFFFFFFFF.
__device__ __forceinline__ bool hasSent(unsigned long long v) {
    return ((unsigned)v == 0xFFFFFFFFu) || ((unsigned)(v >> 32) == 0xFFFFFFFFu);
}

// ---------------- fp32 -> bf16 converter ----------------
__global__ void f2b_kernel(const float* __restrict__ s, bf16* __restrict__ d, int n) {
    int idx = blockIdx.x * blockDim.x + threadIdx.x;
    int stride = gridDim.x * blockDim.x;
    for (int i = idx * 4; i < n; i += stride * 4) {
        float4 v = *reinterpret_cast<const float4*>(s + i);
        ushort4 u;
        u.x = bfbits(v.x); u.y = bfbits(v.y); u.z = bfbits(v.z); u.w = bfbits(v.w);
        *reinterpret_cast<ushort4*>(d + i) = u;
    }
}

// ---------------- sentinel fill for write-once h histories ----------------
__global__ void fill_sentinel(uint4* __restrict__ p, int n16) {
    int i = blockIdx.x * blockDim.x + threadIdx.x;
    int stride = gridDim.x * blockDim.x;
    uint4 v; v.x = v.y = v.z = v.w = 0xFFFFFFFFu;
    for (; i < n16; i += stride) p[i] = v;
}

// ---------------- init states (slot 0 of each history) ----------------
__global__ void init_state_kernel(const float* __restrict__ eh, const float* __restrict__ ec,
                                  float* __restrict__ hf, float* __restrict__ cf,
                                  bf16* __restrict__ h0h, bf16* __restrict__ h1h) {
    int idx = blockIdx.x * blockDim.x + threadIdx.x;
    if (idx >= 2 * 32 * 512) return;
    int l = idx >> 14;          // / 16384
    int rem = idx & 16383;
    hf[idx] = eh[idx];
    cf[idx] = ec[idx];
    bf16 hv = __float2bfloat16(eh[idx]);
    if (!l) h0h[rem] = hv;      // history slot 0 = initial state
    else    h1h[rem] = hv;
}

// ---------------- tail: final states -> d_out ----------------
__global__ void tail_kernel(const float* __restrict__ hf, const float* __restrict__ cf,
                            float* __restrict__ out) {
    int idx = blockIdx.x * blockDim.x + threadIdx.x;
    if (idx >= 2 * 32 * 512) return;
    out[1048576 + idx] = hf[idx];
    out[1048576 + 32768 + idx] = cf[idx];
}

// ---------------- bf16 MFMA GEMM: C[M,N] = A[M,K] @ W[N,K]^T (+bias) ----------------
__global__ __launch_bounds__(256) void gemm_bt(
    const bf16* __restrict__ A, const bf16* __restrict__ W,
    const float* __restrict__ bias,
    float* __restrict__ Cf, bf16* __restrict__ Cb,
    int M, int N, int K) {
    __shared__ __align__(16) bf16 As[64][72];
    __shared__ __align__(16) bf16 Bs[64][72];
    const int tid = threadIdx.x;
    const int wave = tid >> 6, lane = tid & 63;
    const int lr = lane & 15, lq = lane >> 4;
    const int m0 = blockIdx.y * 64, n0 = blockIdx.x * 64;

    v4f acc[4];
#pragma unroll
    for (int n = 0; n < 4; ++n) acc[n] = (v4f){0.f, 0.f, 0.f, 0.f};

    for (int k0 = 0; k0 < K; k0 += 64) {
        __syncthreads();
#pragma unroll
        for (int c = tid; c < 512; c += 256) {
            int row = c >> 3, c8 = (c & 7) * 8;
            *reinterpret_cast<v8s*>(&As[row][c8]) =
                *reinterpret_cast<const v8s*>(A + (size_t)(m0 + row) * K + k0 + c8);
            *reinterpret_cast<v8s*>(&Bs[row][c8]) =
                *reinterpret_cast<const v8s*>(W + (size_t)(n0 + row) * K + k0 + c8);
        }
        __syncthreads();
#pragma unroll
        for (int kk = 0; kk < 2; ++kk) {
            v8s a = *reinterpret_cast<const v8s*>(&As[wave * 16 + lr][kk * 32 + lq * 8]);
#pragma unroll
            for (int n = 0; n < 4; ++n) {
                v8s b = *reinterpret_cast<const v8s*>(&Bs[n * 16 + lr][kk * 32 + lq * 8]);
                acc[n] = __builtin_amdgcn_mfma_f32_16x16x32_bf16(a, b, acc[n], 0, 0, 0);
            }
        }
    }
#pragma unroll
    for (int n = 0; n < 4; ++n) {
        int col = n0 + n * 16 + lr;
        float bv = bias ? bias[col] : 0.0f;
#pragma unroll
        for (int r = 0; r < 4; ++r) {
            int row = m0 + wave * 16 + lq * 4 + r;
            float v = acc[n][r] + bv;
            if (Cf) Cf[(size_t)row * N + col] = v;
            if (Cb) Cb[(size_t)row * N + col] = __float2bfloat16(v);
        }
    }
}

// ---------------- persistent 2-layer pipelined LSTM stack ----------------
// 64 WGs x 256 thr, co-resident. WGs 0..31: layer 0 (WG j owns hidden cols
// [j*16,j*16+16), wave w = gate w). WGs 32..63: layer 1.
//
// Data-is-the-signal protocol (no flags, no grid barrier, no producer drain):
//  - h goes to write-once history slots prefilled with sentinel 0xFFFFFFFF.
//  - Producer: stores h (relaxed agent u32) and moves on. Nothing else.
//  - Consumer: each thread's 16 u64s all come from ONE producer WG (cols
//    (8*tid)&511..+8), whose 256 stores issue within a few cycles of each
//    other. So the thread atomically polls only its FIRST u64 (uncached ->
//    no L2 poisoning; single word -> no R2 re-poll storm). After detect:
//    compiler fence, then CACHED bulk load of the other 15 u64s (fresh line
//    -> IC fetch, L2-fill shared by the 8 consumer WGs per XCD), then
//    sentinel-validate with atomic reload as a rare-straggler backstop.
//  - Layers fully decoupled: layer0 WGs are paced only by their own
//    all-to-all (max 1-step skew); layer1 free-runs behind layer0
//    (write-once slots = no WAR); its h0-input detect is pre-satisfied in
//    steady state.
// Serial chain per step: store -> IC visibility -> poll detect -> cached
// load -> LDS stage -> MFMA -> pointwise. (R1's drain + flag hops removed.)
__global__ __launch_bounds__(256, 1) void lstm2_persist(
    int T, int t0,
    bf16* __restrict__ h0hist, bf16* __restrict__ h1hist, // write-once histories
    float* __restrict__ hf, float* __restrict__ cf,    // [2][32*512] fp32 state
    const bf16* __restrict__ Whh0,                     // [2048][512]
    const bf16* __restrict__ Wih1, const bf16* __restrict__ Whh1,
    const float* __restrict__ xpf,                     // layer0 fp32 xp [(b*T+t)*2048]
    const bf16* __restrict__ xpb,                      // layer0 bf16 xp (alt)
    const float* __restrict__ bih0, const float* __restrict__ bhh0,
    const float* __restrict__ bih1, const float* __restrict__ bhh1,
    float* __restrict__ outf, long out_stride_b)       // layer1 fp32 h seq (or null)
{
    __shared__ __align__(16) bf16 hs_h[32][520];      // own h(t-1); +8 pad
    __shared__ __align__(16) bf16 hs_x[32][520];      // layer1: h0(t)
    __shared__ float gs[4][32][16];
    __shared__ float bias_s[4][16];

    const int tid = threadIdx.x;
    const int layer = blockIdx.x >> 5;
    const int jj = blockIdx.x & 31;
    const int wave = tid >> 6, lane = tid & 63;
    const int lr = lane & 15, lq = lane >> 4;
    const int hc0 = jj * 16;

    const float* bih_l = layer ? bih1 : bih0;
    const float* bhh_l = layer ? bhh1 : bhh0;
    if (tid < 64) {
        int g = tid >> 4, col = tid & 15;
        bias_s[g][col] = bih_l[g * 512 + hc0 + col] + bhh_l[g * 512 + hc0 + col];
    }

    // pointwise ownership: batch pb, cols pc & pc+1 (c register-resident)
    const int pb = tid >> 3;
    const int pc = (tid & 7) * 2;
    const int pgc = hc0 + pc;

    float* hf_l = hf + (size_t)layer * 16384;
    float* cf_l = cf + (size_t)layer * 16384;
    float c0, c1;
    {
        size_t sidx = (size_t)pb * 512 + pgc;
        c0 = cf_l[sidx]; c1 = cf_l[sidx + 1];
    }

    // Whh slice pinned in registers (64 VGPRs / thread).
    v8s breg_hh[16];
    {
        const bf16* Whh_l = layer ? Whh1 : Whh0;
        const bf16* wrow = Whh_l + (size_t)(wave * 512 + hc0 + lr) * 512 + lq * 8;
#pragma unroll
        for (int kk = 0; kk < 16; ++kk)
            breg_hh[kk] = *reinterpret_cast<const v8s*>(wrow + kk * 32);
    }
    // Layer1: Wih slice also in registers (64 more VGPRs; fine at 1 WG/CU).
    v8s breg_ih[16];
    if (layer) {
        const bf16* wrow = Wih1 + (size_t)(wave * 512 + hc0 + lr) * 512 + lq * 8;
#pragma unroll
        for (int kk = 0; kk < 16; ++kk)
            breg_ih[kk] = *reinterpret_cast<const v8s*>(wrow + kk * 32);
    }
    __syncthreads();

    // staging geometry: thread tid covers v8s at element tid*8 + i*2048,
    // LDS row (tid>>6)+4i, col (tid*8)&511; as u64s: index tid*2 + i*512 (+1)
    const int st_row = tid >> 6;
    const int st_col = (tid * 8) & 511;

    auto load_xp = [&](int t, float* xv) {
        if (xpf) {
            const float* xp = xpf + ((size_t)pb * T + t) * 2048;
            float2 a = *reinterpret_cast<const float2*>(xp + pgc);
            float2 b = *reinterpret_cast<const float2*>(xp + 512 + pgc);
            float2 c = *reinterpret_cast<const float2*>(xp + 1024 + pgc);
            float2 d = *reinterpret_cast<const float2*>(xp + 1536 + pgc);
            xv[0] = a.x; xv[1] = a.y; xv[2] = b.x; xv[3] = b.y;
            xv[4] = c.x; xv[5] = c.y; xv[6] = d.x; xv[7] = d.y;
        } else {
            const bf16* xp = xpb + ((size_t)pb * T + t) * 2048;
            unsigned a = *reinterpret_cast<const unsigned*>(xp + pgc);
            unsigned b = *reinterpret_cast<const unsigned*>(xp + 512 + pgc);
            unsigned c = *reinterpret_cast<const unsigned*>(xp + 1024 + pgc);
            unsigned d = *reinterpret_cast<const unsigned*>(xp + 1536 + pgc);
            xv[0] = bf2f(a & 0xffff); xv[1] = bf2f(a >> 16);
            xv[2] = bf2f(b & 0xffff); xv[3] = bf2f(b >> 16);
            xv[4] = bf2f(c & 0xffff); xv[5] = bf2f(c >> 16);
            xv[6] = bf2f(d & 0xffff); xv[7] = bf2f(d >> 16);
        }
    };

    float xcur[8];
    if (!layer) load_xp(0, xcur);

    bf16* own_base = layer ? h1hist : h0hist;

    for (int t = 0; t < T; ++t) {
        const bf16* own_src = own_base + (size_t)(t0 + t) * 16384;       // h(t-1)
        bf16* own_dst       = own_base + (size_t)(t0 + t + 1) * 16384;   // h(t)

        const unsigned long long* srcH =
            reinterpret_cast<const unsigned long long*>(own_src);
        const unsigned long long* srcX = layer
            ? reinterpret_cast<const unsigned long long*>(
                  h0hist + (size_t)(t0 + t + 1) * 16384)                 // h0(t)
            : nullptr;

        unsigned long long rh[16], rx[16];

        // ---- per-thread detect: atomically poll FIRST own u64 only ----
        {
            unsigned long long h0 = __hip_atomic_load(srcH + tid * 2,
                                        __ATOMIC_RELAXED, __HIP_MEMORY_SCOPE_AGENT);
            if (layer) {
                unsigned long long x0 = __hip_atomic_load(srcX + tid * 2,
                                            __ATOMIC_RELAXED, __HIP_MEMORY_SCOPE_AGENT);
                while (hasSent(h0) || hasSent(x0)) {
                    if (hasSent(h0))
                        h0 = __hip_atomic_load(srcH + tid * 2,
                                 __ATOMIC_RELAXED, __HIP_MEMORY_SCOPE_AGENT);
                    if (hasSent(x0))
                        x0 = __hip_atomic_load(srcX + tid * 2,
                                 __ATOMIC_RELAXED, __HIP_MEMORY_SCOPE_AGENT);
                }
                rx[0] = x0;
            } else {
                while (hasSent(h0))
                    h0 = __hip_atomic_load(srcH + tid * 2,
                             __ATOMIC_RELAXED, __HIP_MEMORY_SCOPE_AGENT);
            }
            rh[0] = h0;
        }
        // fence: forbid the compiler from hoisting the cached bulk loads
        // above the detect poll (would re-create R3's L2 sentinel poisoning).
        asm volatile("" ::: "memory");

        // ---- cached bulk load of the remaining 15 u64s (L2-shared fill) ----
        rh[1] = srcH[tid * 2 + 1];
#pragma unroll
        for (int i = 1; i < 8; ++i) {
            rh[2 * i]     = srcH[tid * 2 + i * 512];
            rh[2 * i + 1] = srcH[tid * 2 + i * 512 + 1];
        }
        if (layer) {
            rx[1] = srcX[tid * 2 + 1];
#pragma unroll
            for (int i = 1; i < 8; ++i) {
                rx[2 * i]     = srcX[tid * 2 + i * 512];
                rx[2 * i + 1] = srcX[tid * 2 + i * 512 + 1];
            }
        }

        // ---- sentinel validation + atomic reload of rare stragglers ----
        for (;;) {
            bool again = false;
#pragma unroll
            for (int k = 1; k < 16; ++k) {
                if (hasSent(rh[k])) {
                    rh[k] = __hip_atomic_load(
                        srcH + tid * 2 + (k >> 1) * 512 + (k & 1),
                        __ATOMIC_RELAXED, __HIP_MEMORY_SCOPE_AGENT);
                    again = true;
                }
            }
            if (layer) {
#pragma unroll
                for (int k = 1; k < 16; ++k) {
                    if (hasSent(rx[k])) {
                        rx[k] = __hip_atomic_load(
                            srcX + tid * 2 + (k >> 1) * 512 + (k & 1),
                            __ATOMIC_RELAXED, __HIP_MEMORY_SCOPE_AGENT);
                        again = true;
                    }
                }
            }
            if (!again) break;
        }

        // ---- stage -> LDS ----
        if (layer) {
#pragma unroll
            for (int i = 0; i < 8; ++i) {
                union { unsigned long long u[2]; v8s v; } w;
                w.u[0] = rx[2 * i]; w.u[1] = rx[2 * i + 1];
                *reinterpret_cast<v8s*>(&hs_x[st_row + 4 * i][st_col]) = w.v;
            }
        }
#pragma unroll
        for (int i = 0; i < 8; ++i) {
            union { unsigned long long u[2]; v8s v; } w;
            w.u[0] = rh[2 * i]; w.u[1] = rh[2 * i + 1];
            *reinterpret_cast<v8s*>(&hs_h[st_row + 4 * i][st_col]) = w.v;
        }
        __syncthreads();

        // ---- gate GEMM from LDS; 4 independent MFMA chains for ILP ----
        v4f ax0 = (v4f){0.f, 0.f, 0.f, 0.f};
        v4f ax1 = (v4f){0.f, 0.f, 0.f, 0.f};
        v4f ah0 = (v4f){0.f, 0.f, 0.f, 0.f};
        v4f ah1 = (v4f){0.f, 0.f, 0.f, 0.f};
        if (layer) {
#pragma unroll
            for (int kk = 0; kk < 16; ++kk) {
                v8s a0x = *reinterpret_cast<const v8s*>(&hs_x[lr][lq * 8 + kk * 32]);
                v8s a1x = *reinterpret_cast<const v8s*>(&hs_x[16 + lr][lq * 8 + kk * 32]);
                ax0 = __builtin_amdgcn_mfma_f32_16x16x32_bf16(a0x, breg_ih[kk], ax0, 0, 0, 0);
                ax1 = __builtin_amdgcn_mfma_f32_16x16x32_bf16(a1x, breg_ih[kk], ax1, 0, 0, 0);
                v8s a0h = *reinterpret_cast<const v8s*>(&hs_h[lr][lq * 8 + kk * 32]);
                v8s a1h = *reinterpret_cast<const v8s*>(&hs_h[16 + lr][lq * 8 + kk * 32]);
                ah0 = __builtin_amdgcn_mfma_f32_16x16x32_bf16(a0h, breg_hh[kk], ah0, 0, 0, 0);
                ah1 = __builtin_amdgcn_mfma_f32_16x16x32_bf16(a1h, breg_hh[kk], ah1, 0, 0, 0);
            }
        } else {
#pragma unroll
            for (int kk = 0; kk < 16; kk += 2) {
                v8s a0e = *reinterpret_cast<const v8s*>(&hs_h[lr][lq * 8 + kk * 32]);
                v8s a1e = *reinterpret_cast<const v8s*>(&hs_h[16 + lr][lq * 8 + kk * 32]);
                ax0 = __builtin_amdgcn_mfma_f32_16x16x32_bf16(a0e, breg_hh[kk], ax0, 0, 0, 0);
                ax1 = __builtin_amdgcn_mfma_f32_16x16x32_bf16(a1e, breg_hh[kk], ax1, 0, 0, 0);
                v8s a0o = *reinterpret_cast<const v8s*>(&hs_h[lr][lq * 8 + (kk + 1) * 32]);
                v8s a1o = *reinterpret_cast<const v8s*>(&hs_h[16 + lr][lq * 8 + (kk + 1) * 32]);
                ah0 = __builtin_amdgcn_mfma_f32_16x16x32_bf16(a0o, breg_hh[kk + 1], ah0, 0, 0, 0);
                ah1 = __builtin_amdgcn_mfma_f32_16x16x32_bf16(a1o, breg_hh[kk + 1], ah1, 0, 0, 0);
            }
        }
        v4f acc0 = ax0 + ah0;
        v4f acc1 = ax1 + ah1;
#pragma unroll
        for (int r2 = 0; r2 < 4; ++r2) {
            gs[wave][lq * 4 + r2][lr]      = acc0[r2];
            gs[wave][16 + lq * 4 + r2][lr] = acc1[r2];
        }
        __syncthreads();

        // ---- pointwise: this thread's (pb, pc..pc+1) ----
        float xi0 = layer ? 0.f : xcur[0], xi1 = layer ? 0.f : xcur[1];
        float xf0 = layer ? 0.f : xcur[2], xf1 = layer ? 0.f : xcur[3];
        float xg0 = layer ? 0.f : xcur[4], xg1 = layer ? 0.f : xcur[5];
        float xo0 = layer ? 0.f : xcur[6], xo1 = layer ? 0.f : xcur[7];

        float gi0 = gs[0][pb][pc]     + xi0 + bias_s[0][pc];
        float gi1 = gs[0][pb][pc + 1] + xi1 + bias_s[0][pc + 1];
        float gf0 = gs[1][pb][pc]     + xf0 + bias_s[1][pc];
        float gf1 = gs[1][pb][pc + 1] + xf1 + bias_s[1][pc + 1];
        float gg0 = gs[2][pb][pc]     + xg0 + bias_s[2][pc];
        float gg1 = gs[2][pb][pc + 1] + xg1 + bias_s[2][pc + 1];
        float go0 = gs[3][pb][pc]     + xo0 + bias_s[3][pc];
        float go1 = gs[3][pb][pc + 1] + xo1 + bias_s[3][pc + 1];

        c0 = sigmoidf_(gf0) * c0 + sigmoidf_(gi0) * tanhf_(gg0);
        c1 = sigmoidf_(gf1) * c1 + sigmoidf_(gi1) * tanhf_(gg1);
        float h0v = sigmoidf_(go0) * tanhf_(c0);
        float h1v = sigmoidf_(go1) * tanhf_(c1);

        unsigned hp = (unsigned)bfbits(h0v) | ((unsigned)bfbits(h1v) << 16);
        __hip_atomic_store(reinterpret_cast<unsigned*>(own_dst + (size_t)pb * 512 + pgc),
                           hp, __ATOMIC_RELAXED, __HIP_MEMORY_SCOPE_AGENT);
        if (layer && outf) {
            float2 hv; hv.x = h0v; hv.y = h1v;
            *reinterpret_cast<float2*>(outf + (size_t)pb * out_stride_b + (size_t)t * 512 + pgc) = hv;
        }
        if (t == T - 1) {
            size_t sidx = (size_t)pb * 512 + pgc;
            hf_l[sidx] = h0v; hf_l[sidx + 1] = h1v;
            cf_l[sidx] = c0;  cf_l[sidx + 1] = c1;
        }

        // fence: keep the h store from sinking below the next step's poll
        // loop (deadlock hazard — peers wait on this data).
        asm volatile("" ::: "memory");
        // layer0: xp(t+1) prefetch; latency drains under next step's poll.
        if (!layer && t + 1 < T) load_xp(t + 1, xcur);
    }
}

// ---------------- host orchestration ----------------
extern "C" void kernel_launch(void* const* d_in, const int* in_sizes, int n_in,
                              void* d_out, int out_size, void* d_ws, size_t ws_size,
                              hipStream_t stream) {
    constexpr int B = 32, S = 512, F = 64, I = 512, H = 512, G = 2048;

    const float* x    = (const float*)d_in[0];
    const float* fut  = (const float*)d_in[1];
    const float* eh   = (const float*)d_in[2];
    const float* ec   = (const float*)d_in[3];
    const float* fc_w = (const float*)d_in[4];
    const float* fc_b = (const float*)d_in[5];
    const float* ewih = (const float*)d_in[6];
    const float* ewhh = (const float*)d_in[7];
    const float* ebih = (const float*)d_in[8];
    const float* ebhh = (const float*)d_in[9];
    const float* dwih = (const float*)d_in[10];
    const float* dwhh = (const float*)d_in[11];
    const float* dbih = (const float*)d_in[12];
    const float* dbhh = (const float*)d_in[13];
    float* out = (float*)d_out;

    char* ws = (char*)d_ws;
    size_t off = 0;
    auto alloc = [&](size_t bytes) -> char* {
        char* p = ws + off;
        off += (bytes + 255) & ~(size_t)255;
        return p;
    };

    bf16* x_bf    = (bf16*)alloc((size_t)B * S * I * 2);
    bf16* fut_bf  = (bf16*)alloc((size_t)B * F * I * 2);
    bf16* fcw_bf  = (bf16*)alloc((size_t)H * I * 2);
    bf16* ewih_bf = (bf16*)alloc((size_t)2 * G * H * 2);
    bf16* ewhh_bf = (bf16*)alloc((size_t)2 * G * H * 2);
    bf16* dwih_bf = (bf16*)alloc((size_t)2 * G * H * 2);
    bf16* dwhh_bf = (bf16*)alloc((size_t)2 * G * H * 2);
    bf16* xt_bf   = (bf16*)alloc((size_t)B * S * H * 2);
    float* hf     = (float*)alloc((size_t)2 * B * H * 4);
    float* cf     = (float*)alloc((size_t)2 * B * H * 4);

    // write-once h histories: (S+F+1) slots x [B*H] bf16 each (contiguous pair)
    size_t histb = (size_t)(S + F + 1) * B * H * 2;
    bf16* h0hist = (bf16*)alloc(histb);
    bf16* h1hist = (bf16*)alloc(histb);

    size_t xp32_bytes = (size_t)B * S * G * 4;
    bool xp32 = ws_size >= off + xp32_bytes + 4096;
    float* Xf = nullptr; bf16* Xb = nullptr;
    if (xp32) Xf = (float*)alloc(xp32_bytes);
    else      Xb = (bf16*)alloc((size_t)B * S * G * 2);

    auto cvt = [&](const float* s, bf16* d, int n) {
        int blocks = (n / 4 + 255) / 256;
        if (blocks > 4096) blocks = 4096;
        f2b_kernel<<<blocks, 256, 0, stream>>>(s, d, n);
    };
    cvt(x, x_bf, B * S * I);
    cvt(fut, fut_bf, B * F * I);
    cvt(fc_w, fcw_bf, H * I);
    cvt(ewih, ewih_bf, 2 * G * H);
    cvt(ewhh, ewhh_bf, 2 * G * H);
    cvt(dwih, dwih_bf, 2 * G * H);
    cvt(dwhh, dwhh_bf, 2 * G * H);

    // sentinel-fill both histories (contiguous), THEN write slot-0 states.
    // Dispatch-boundary release/acquire pushes these to IC before persist.
    fill_sentinel<<<2048, 256, 0, stream>>>(
        reinterpret_cast<uint4*>(h0hist), (int)(2 * histb / 16));
    init_state_kernel<<<128, 256, 0, stream>>>(eh, ec, hf, cf, h0hist, h1hist);

    auto gemm = [&](const bf16* A, const bf16* W, const float* bias,
                    float* Cf_, bf16* Cb_, int M, int N, int K) {
        gemm_bt<<<dim3(N / 64, M / 64), 256, 0, stream>>>(A, W, bias, Cf_, Cb_, M, N, K);
    };

    // FC: xt = bf16(x @ fc_w^T + fc_b)
    gemm(x_bf, fcw_bf, fc_b, nullptr, xt_bf, B * S, H, I);

    // ---- Encoder: xp for layer 0 only, then free-running 2-layer persist ----
    gemm(xt_bf, ewih_bf, nullptr, Xf, Xb, B * S, G, H);
    lstm2_persist<<<64, 256, 0, stream>>>(
        S, /*t0=*/0,
        h0hist, h1hist,
        hf, cf,
        ewhh_bf,                              // Whh0
        ewih_bf + (size_t)G * H,              // Wih1
        ewhh_bf + (size_t)G * H,              // Whh1
        Xf, Xb,
        ebih, ebhh, ebih + G, ebhh + G,
        nullptr, 0);

    // ---- Decoder: starts at slot S (= encoder's final h, already in place) ----
    gemm(fut_bf, dwih_bf, nullptr, Xf, Xb, B * F, G, H);
    lstm2_persist<<<64, 256, 0, stream>>>(
        F, /*t0=*/S,
        h0hist, h1hist,
        hf, cf,
        dwhh_bf,
        dwih_bf + (size_t)G * H,
        dwhh_bf + (size_t)G * H,
        Xf, Xb,
        dbih, dbhh, dbih + G, dbhh + G,
        out, (long)F * H);                    // dec_out [B,F,H] fp32

    // ---- Final decoder states ----
    tail_kernel<<<128, 256, 0, stream>>>(hf, cf, out);
}